// Round 3
// baseline (286.060 us; speedup 1.0000x reference)
//
#include <hip/hip_runtime.h>

#define BB  64
#define TT  1024
#define CC  256
#define PP  784     // 28*28
#define HID 512
#define FF  1280    // CC + TT

typedef float v2f __attribute__((ext_vector_type(2)));

// ---------------------------------------------------------------------------
// K1: text GEMM partials, k-split by 4.
// tbp[b][ks][h] = sum_{k in ks-chunk of 256} text[b,k] * W1[k,h]
// ---------------------------------------------------------------------------
__global__ __launch_bounds__(512) void k_text_gemm(const float* __restrict__ text,
                                                   const float* __restrict__ W1,
                                                   float* __restrict__ tbp) {
    const int b  = blockIdx.x;
    const int ks = blockIdx.y;
    const int t  = threadIdx.x;   // 512 threads, one per h
    __shared__ float st[256];
    if (t < 256) st[t] = text[b * TT + ks * 256 + t];
    __syncthreads();
    float acc = 0.f;
    const float* wp = W1 + (size_t)(ks * 256) * HID + t;
    #pragma unroll 4
    for (int k = 0; k < 256; ++k)
        acc = fmaf(st[k], wp[(size_t)k * HID], acc);
    tbp[(b * 4 + ks) * HID + t] = acc;
}

// ---------------------------------------------------------------------------
// K2 (hot): fused vision GEMM + bias + ReLU + dot(W2) -> scores[b,p]
// Block: 448 thr = 7 waves; grid (7, B): 7 blocks * 7 waves * 16 px = 784, exact.
// Wave owns 16 pixels: W1 L2 traffic 3.2 GB (8px) -> 1.6 GB, hidden under the
// ~84 us fp32 VALU floor. Lane owns h = 8*lane..+7.
// acc: v2f[16][4] (~128 VGPR) -> v_pk_fma_f32 if available, else v_fma.
// Vision loads: 4x float4 same-addr across lanes (broadcast, 1 req/wave).
// W1 loads: 2x float4 coalesced (full 2 KB row per wave per c).
// No LDS, no barriers.
// ---------------------------------------------------------------------------
__global__ __launch_bounds__(448, 2) void k_vision_score(const float* __restrict__ vision,
                                                         const float* __restrict__ W1,
                                                         const float* __restrict__ b1,
                                                         const float* __restrict__ W2,
                                                         const float* __restrict__ b2,
                                                         const float* __restrict__ tbp,
                                                         float* __restrict__ scores) {
    const int tile = blockIdx.x;            // 7 tiles of 112 pixels
    const int b    = blockIdx.y;
    const int lane = threadIdx.x & 63;
    const int wid  = threadIdx.x >> 6;      // 7 waves
    const int p0   = tile * 112 + wid * 16; // this wave's 16 pixels (always < 784)
    const int h0   = lane * 8;

    const float* vb  = vision + (size_t)b * (CC * PP) + p0;
    const float* w1p = W1 + (size_t)TT * HID + h0;

    v2f acc[16][4];
    #pragma unroll
    for (int i = 0; i < 16; ++i)
        #pragma unroll
        for (int j = 0; j < 4; ++j) acc[i][j] = (v2f){0.f, 0.f};

    #pragma unroll 2
    for (int c = 0; c < CC; ++c) {
        const float* vc = vb + (size_t)c * PP;
        const float4 pv0 = *(const float4*)(vc);
        const float4 pv1 = *(const float4*)(vc + 4);
        const float4 pv2 = *(const float4*)(vc + 8);
        const float4 pv3 = *(const float4*)(vc + 12);
        const float4 wa  = *(const float4*)(w1p + (size_t)c * HID);
        const float4 wb  = *(const float4*)(w1p + (size_t)c * HID + 4);
        const float pr[16] = {pv0.x, pv0.y, pv0.z, pv0.w,
                              pv1.x, pv1.y, pv1.z, pv1.w,
                              pv2.x, pv2.y, pv2.z, pv2.w,
                              pv3.x, pv3.y, pv3.z, pv3.w};
        v2f wrv[4];
        wrv[0] = (v2f){wa.x, wa.y}; wrv[1] = (v2f){wa.z, wa.w};
        wrv[2] = (v2f){wb.x, wb.y}; wrv[3] = (v2f){wb.z, wb.w};
        #pragma unroll
        for (int i = 0; i < 16; ++i) {
            const v2f pi = (v2f){pr[i], pr[i]};
            #pragma unroll
            for (int j = 0; j < 4; ++j)
                acc[i][j] = __builtin_elementwise_fma(pi, wrv[j], acc[i][j]);
        }
    }

    // tb[b,h] = b1[h] + sum of 4 k-split text partials; W2 pairs
    v2f tbv[4], w2v[4];
    {
        const float* tp = tbp + (size_t)b * 4 * HID + h0;
        #pragma unroll
        for (int j = 0; j < 8; ++j) {
            const float v = b1[h0 + j] + tp[j] + tp[HID + j] + tp[2 * HID + j] + tp[3 * HID + j];
            ((float*)tbv)[j] = v;
        }
        const float4 wz0 = *(const float4*)(W2 + h0);
        const float4 wz1 = *(const float4*)(W2 + h0 + 4);
        w2v[0] = (v2f){wz0.x, wz0.y}; w2v[1] = (v2f){wz0.z, wz0.w};
        w2v[2] = (v2f){wz1.x, wz1.y}; w2v[3] = (v2f){wz1.z, wz1.w};
    }
    const float b2v = b2[0];

    #pragma unroll
    for (int i = 0; i < 16; ++i) {
        float s = 0.f;
        #pragma unroll
        for (int j = 0; j < 4; ++j) {
            const float h0v = fmaxf(tbv[j].x + acc[i][j].x, 0.f);
            const float h1v = fmaxf(tbv[j].y + acc[i][j].y, 0.f);
            s = fmaf(h0v, w2v[j].x, s);
            s = fmaf(h1v, w2v[j].y, s);
        }
        #pragma unroll
        for (int off = 32; off > 0; off >>= 1)
            s += __shfl_xor(s, off, 64);   // reduce over all 512 h (64 lanes x 8)
        if (lane == 0) scores[b * PP + p0 + i] = s + b2v;
    }
}

// ---------------------------------------------------------------------------
// K3: softmax over P per batch row (in-place scores -> weights),
// plus passthrough copy of text into out[b, 256:1280].
// ---------------------------------------------------------------------------
__global__ __launch_bounds__(256) void k_softmax_copy(float* __restrict__ sw,
                                                      const float* __restrict__ text,
                                                      float* __restrict__ out) {
    const int b   = blockIdx.x;
    const int tid = threadIdx.x;
    const int lane = tid & 63, wid = tid >> 6;   // 4 waves
    __shared__ float red[4];

    float v[4]; int cnt = 0;
    float m = -3.4e38f;
    for (int p = tid; p < PP; p += 256) { v[cnt] = sw[b * PP + p]; m = fmaxf(m, v[cnt]); ++cnt; }
    #pragma unroll
    for (int off = 32; off > 0; off >>= 1) m = fmaxf(m, __shfl_xor(m, off, 64));
    if (lane == 0) red[wid] = m;
    __syncthreads();
    m = fmaxf(fmaxf(red[0], red[1]), fmaxf(red[2], red[3]));
    __syncthreads();  // red about to be reused

    float ssum = 0.f;
    for (int i = 0; i < cnt; ++i) { v[i] = expf(v[i] - m); ssum += v[i]; }
    #pragma unroll
    for (int off = 32; off > 0; off >>= 1) ssum += __shfl_xor(ssum, off, 64);
    if (lane == 0) red[wid] = ssum;
    __syncthreads();
    const float inv = 1.f / (red[0] + red[1] + red[2] + red[3]);

    cnt = 0;
    for (int p = tid; p < PP; p += 256) sw[b * PP + p] = v[cnt++] * inv;

    // text passthrough: out[b, 256:1280] = text[b, :]
    for (int j = tid; j < TT; j += 256) out[b * FF + CC + j] = text[b * TT + j];
}

// ---------------------------------------------------------------------------
// K4: pooled[b,c] = sum_p vision[b,c,p] * weights[b,p]  -> out[b, 0:256]
// Wave per 16 channels; vectorized float4 loads; weights staged once in LDS.
// ---------------------------------------------------------------------------
__global__ __launch_bounds__(256) void k_pool(const float* __restrict__ vision,
                                              const float* __restrict__ wts,
                                              float* __restrict__ out) {
    const int cg = blockIdx.x;   // 4 channel groups of 64
    const int b  = blockIdx.y;
    const int tid = threadIdx.x, lane = tid & 63, wid = tid >> 6;  // 4 waves
    __shared__ float wl[PP];
    {
        const int i = tid * 4;
        if (i < PP) *(float4*)&wl[i] = *(const float4*)&wts[b * PP + i];
    }
    __syncthreads();
    #pragma unroll
    for (int ci = 0; ci < 16; ++ci) {
        const int c = cg * 64 + wid * 16 + ci;
        const float* vr = vision + (size_t)b * (CC * PP) + (size_t)c * PP;
        float acc = 0.f;
        #pragma unroll
        for (int k = 0; k < 4; ++k) {
            const int p4 = (lane + 64 * k) * 4;
            if (p4 < PP) {
                const float4 vv = *(const float4*)(vr + p4);
                const float4 ww = *(const float4*)&wl[p4];
                acc = fmaf(vv.x, ww.x, acc);
                acc = fmaf(vv.y, ww.y, acc);
                acc = fmaf(vv.z, ww.z, acc);
                acc = fmaf(vv.w, ww.w, acc);
            }
        }
        #pragma unroll
        for (int off = 32; off > 0; off >>= 1) acc += __shfl_xor(acc, off, 64);
        if (lane == 0) out[b * FF + c] = acc;
    }
}

// ---------------------------------------------------------------------------
extern "C" void kernel_launch(void* const* d_in, const int* in_sizes, int n_in,
                              void* d_out, int out_size, void* d_ws, size_t ws_size,
                              hipStream_t stream) {
    const float* text   = (const float*)d_in[0];
    const float* vision = (const float*)d_in[1];
    const float* W1     = (const float*)d_in[2];
    const float* b1     = (const float*)d_in[3];
    const float* W2     = (const float*)d_in[4];
    const float* b2     = (const float*)d_in[5];
    float* out = (float*)d_out;

    // workspace layout (fp32): tbp 64*4*512 | scores/weights 64*784  (~712 KB)
    float* tbp = (float*)d_ws;
    float* sw  = tbp + BB * 4 * HID;

    k_text_gemm   <<<dim3(BB, 4), 512, 0, stream>>>(text, W1, tbp);
    k_vision_score<<<dim3(7, BB), 448, 0, stream>>>(vision, W1, b1, W2, b2, tbp, sw);
    k_softmax_copy<<<BB, 256, 0, stream>>>(sw, text, out);
    k_pool        <<<dim3(4, BB), 256, 0, stream>>>(vision, sw, out);
}

// Round 4
// 185.015 us; speedup vs baseline: 1.5461x; 1.5461x over previous
//
#include <hip/hip_runtime.h>

#define BB  64
#define TT  1024
#define CC  256
#define PP  784     // 28*28
#define HID 512
#define FF  1280    // CC + TT

typedef float v4f __attribute__((ext_vector_type(4)));
typedef short v8s __attribute__((ext_vector_type(8)));

// round-to-nearest-even bf16; returns the f32 bit pattern of the bf16 value
__device__ inline unsigned int bf16_rne_bits(float x) {
    unsigned int u = __float_as_uint(x);
    unsigned int r = u + 0x7FFFu + ((u >> 16) & 1u);
    return r & 0xFFFF0000u;
}

// ---------------------------------------------------------------------------
// K0: precompute W1 vision-half as bf16 hi/lo in MFMA B-fragment image order:
// W1T[hh (2)][cstep (8)][h' (256)][granule (4)][e (8)] ; elem (h,c):
//   hh=h>>8, h'=h&255, cstep=c>>5, g=(c>>3)&3, e=c&7.  512 KB total, done once.
// ---------------------------------------------------------------------------
__global__ __launch_bounds__(256) void k_w1t(const float* __restrict__ W1,
                                             unsigned short* __restrict__ w1t_hi,
                                             unsigned short* __restrict__ w1t_lo) {
    const int id = blockIdx.x * 256 + threadIdx.x;   // 16384 threads
    const int h  = id & 511;
    const int cg = id >> 9;                          // 0..31
    const int cstep = cg >> 2, g = cg & 3;
    const float* W1v = W1 + (size_t)TT * HID;
    unsigned int hw[4], lw[4];
    #pragma unroll
    for (int k = 0; k < 4; ++k) {
        const int c0 = cstep * 32 + g * 8 + 2 * k;
        float x0 = W1v[(size_t)c0 * HID + h];
        float x1 = W1v[(size_t)(c0 + 1) * HID + h];
        unsigned int h0 = bf16_rne_bits(x0), h1 = bf16_rne_bits(x1);
        unsigned int l0 = bf16_rne_bits(x0 - __uint_as_float(h0));
        unsigned int l1 = bf16_rne_bits(x1 - __uint_as_float(h1));
        hw[k] = (h0 >> 16) | (h1 & 0xFFFF0000u);
        lw[k] = (l0 >> 16) | (l1 & 0xFFFF0000u);
    }
    const size_t eoff = ((size_t)((h >> 8) * 8 + cstep) * 256 + (h & 255)) * 32 + g * 8;
    *(int4*)(&w1t_hi[eoff]) = make_int4(hw[0], hw[1], hw[2], hw[3]);
    *(int4*)(&w1t_lo[eoff]) = make_int4(lw[0], lw[1], lw[2], lw[3]);
}

// ---------------------------------------------------------------------------
// K1: text GEMM partials, k-split by 4 (unchanged, proven).
// ---------------------------------------------------------------------------
__global__ __launch_bounds__(512) void k_text_gemm(const float* __restrict__ text,
                                                   const float* __restrict__ W1,
                                                   float* __restrict__ tbp) {
    const int b  = blockIdx.x;
    const int ks = blockIdx.y;
    const int t  = threadIdx.x;
    __shared__ float st[256];
    if (t < 256) st[t] = text[b * TT + ks * 256 + t];
    __syncthreads();
    float acc = 0.f;
    const float* wp = W1 + (size_t)(ks * 256) * HID + t;
    #pragma unroll 4
    for (int k = 0; k < 256; ++k)
        acc = fmaf(st[k], wp[(size_t)k * HID], acc);
    tbp[(b * 4 + ks) * HID + t] = acc;
}

// ---------------------------------------------------------------------------
// K2 (hot): vision GEMM via bf16 hi/lo split MFMA (3 terms), fused epilogue
// bias + text-partials + ReLU + dot(W2) -> atomicAdd partial scores.
// Block = 112 px x 256 h-half, 4 waves; wave = 7 M-tiles x 4 N-tiles of
// mfma_f32_16x16x32_bf16. 784 = 7*112 exact. KC=32, 8 K-steps, single-buffer
// LDS 46 KB, 2 barriers/K-step, 2 blocks/CU for overlap.
// ---------------------------------------------------------------------------
__global__ __launch_bounds__(256, 2) void k_vision_mfma(
        const float* __restrict__ vision,
        const unsigned short* __restrict__ w1t_hi,
        const unsigned short* __restrict__ w1t_lo,
        const float* __restrict__ b1,
        const float* __restrict__ W2,
        const float* __restrict__ tbp,
        float* __restrict__ scores) {
    const int ptile = blockIdx.x;   // 0..6
    const int hh    = blockIdx.y;   // 0..1
    const int b     = blockIdx.z;
    const int tid   = threadIdx.x;
    const int lane  = tid & 63;
    const int w     = tid >> 6;     // 4 waves
    const int l15   = lane & 15, lg = lane >> 4;

    // LDS regions (bytes): B_hi [0,16384) B_lo [16384,32768)
    //                      A_hi [32768,39936) A_lo [39936,47104)
    __shared__ int4 lds4[47104 / 16];
    char* lds = (char*)lds4;

    v4f acc[7][4];
    #pragma unroll
    for (int m = 0; m < 7; ++m)
        #pragma unroll
        for (int n = 0; n < 4; ++n) acc[m][n] = (v4f){0.f, 0.f, 0.f, 0.f};

    const size_t vbase = (size_t)b * (CC * PP) + ptile * 112;

    for (int ks = 0; ks < 8; ++ks) {
        // ---- stage B: pure 16B-granule copy of pre-packed W1T chunk ----
        {
            const size_t boff = (size_t)(hh * 8 + ks) * 8192;   // elems
            const int4* srcH = (const int4*)(w1t_hi + boff);
            const int4* srcL = (const int4*)(w1t_lo + boff);
            int4* dstH = (int4*)(lds + 0);
            int4* dstL = (int4*)(lds + 16384);
            #pragma unroll
            for (int r = 0; r < 4; ++r) {
                dstH[r * 256 + tid] = srcH[r * 256 + tid];
                dstL[r * 256 + tid] = srcL[r * 256 + tid];
            }
        }
        // ---- stage A: load f32 pixels, split hi/lo, pack k-contiguous ----
        if (tid < 224) {
            const int px    = tid >> 1;
            const int chalf = tid & 1;
            float xv[16];
            #pragma unroll
            for (int j = 0; j < 16; ++j) {
                const int c = ks * 32 + chalf * 16 + j;
                xv[j] = vision[vbase + (size_t)c * PP + px];
            }
            unsigned int hw[8], lw[8];
            #pragma unroll
            for (int k = 0; k < 8; ++k) {
                unsigned int h0 = bf16_rne_bits(xv[2 * k]);
                unsigned int h1 = bf16_rne_bits(xv[2 * k + 1]);
                unsigned int l0 = bf16_rne_bits(xv[2 * k] - __uint_as_float(h0));
                unsigned int l1 = bf16_rne_bits(xv[2 * k + 1] - __uint_as_float(h1));
                hw[k] = (h0 >> 16) | (h1 & 0xFFFF0000u);
                lw[k] = (l0 >> 16) | (l1 & 0xFFFF0000u);
            }
            int4* ah = (int4*)(lds + 32768) + (px * 4 + chalf * 2);
            int4* al = (int4*)(lds + 39936) + (px * 4 + chalf * 2);
            ah[0] = make_int4(hw[0], hw[1], hw[2], hw[3]);
            ah[1] = make_int4(hw[4], hw[5], hw[6], hw[7]);
            al[0] = make_int4(lw[0], lw[1], lw[2], lw[3]);
            al[1] = make_int4(lw[4], lw[5], lw[6], lw[7]);
        }
        __syncthreads();
        // ---- compute: 84 MFMA per wave per K-step ----
        v8s ahf[7], alf[7];
        #pragma unroll
        for (int m = 0; m < 7; ++m) {
            const int row = m * 16 + l15;
            ahf[m] = *(const v8s*)(lds + 32768 + (row * 4 + lg) * 16);
            alf[m] = *(const v8s*)(lds + 39936 + (row * 4 + lg) * 16);
        }
        #pragma unroll
        for (int n = 0; n < 4; ++n) {
            const int hrow = w * 64 + n * 16 + l15;
            const v8s bh = *(const v8s*)(lds + 0     + (hrow * 4 + lg) * 16);
            const v8s bl = *(const v8s*)(lds + 16384 + (hrow * 4 + lg) * 16);
            #pragma unroll
            for (int m = 0; m < 7; ++m) {
                acc[m][n] = __builtin_amdgcn_mfma_f32_16x16x32_bf16(ahf[m], bh, acc[m][n], 0, 0, 0);
                acc[m][n] = __builtin_amdgcn_mfma_f32_16x16x32_bf16(ahf[m], bl, acc[m][n], 0, 0, 0);
                acc[m][n] = __builtin_amdgcn_mfma_f32_16x16x32_bf16(alf[m], bh, acc[m][n], 0, 0, 0);
            }
        }
        __syncthreads();
    }

    // ---- epilogue: +text/bias, ReLU, *W2, reduce over h, atomic partial ----
    float tbn[4], w2n[4];
    #pragma unroll
    for (int n = 0; n < 4; ++n) {
        const int hglob = hh * 256 + w * 64 + n * 16 + l15;
        const float* tp = tbp + (size_t)b * 4 * HID + hglob;
        tbn[n] = b1[hglob] + tp[0] + tp[HID] + tp[2 * HID] + tp[3 * HID];
        w2n[n] = W2[hglob];
    }
    const int px0 = ptile * 112 + lg * 4;
    #pragma unroll
    for (int m = 0; m < 7; ++m) {
        #pragma unroll
        for (int r = 0; r < 4; ++r) {
            float s = 0.f;
            #pragma unroll
            for (int n = 0; n < 4; ++n)
                s += fmaxf(acc[m][n][r] + tbn[n], 0.f) * w2n[n];
            s += __shfl_xor(s, 1, 64);
            s += __shfl_xor(s, 2, 64);
            s += __shfl_xor(s, 4, 64);
            s += __shfl_xor(s, 8, 64);
            if (l15 == 0)
                atomicAdd(&scores[b * PP + px0 + m * 16 + r], s);
        }
    }
}

// ---------------------------------------------------------------------------
// K3: softmax over P per batch row (in-place) + text passthrough (unchanged).
// (b2 omitted everywhere: softmax is shift-invariant.)
// ---------------------------------------------------------------------------
__global__ __launch_bounds__(256) void k_softmax_copy(float* __restrict__ sw,
                                                      const float* __restrict__ text,
                                                      float* __restrict__ out) {
    const int b   = blockIdx.x;
    const int tid = threadIdx.x;
    const int lane = tid & 63, wid = tid >> 6;
    __shared__ float red[4];

    float v[4]; int cnt = 0;
    float m = -3.4e38f;
    for (int p = tid; p < PP; p += 256) { v[cnt] = sw[b * PP + p]; m = fmaxf(m, v[cnt]); ++cnt; }
    #pragma unroll
    for (int off = 32; off > 0; off >>= 1) m = fmaxf(m, __shfl_xor(m, off, 64));
    if (lane == 0) red[wid] = m;
    __syncthreads();
    m = fmaxf(fmaxf(red[0], red[1]), fmaxf(red[2], red[3]));
    __syncthreads();

    float ssum = 0.f;
    for (int i = 0; i < cnt; ++i) { v[i] = expf(v[i] - m); ssum += v[i]; }
    #pragma unroll
    for (int off = 32; off > 0; off >>= 1) ssum += __shfl_xor(ssum, off, 64);
    if (lane == 0) red[wid] = ssum;
    __syncthreads();
    const float inv = 1.f / (red[0] + red[1] + red[2] + red[3]);

    cnt = 0;
    for (int p = tid; p < PP; p += 256) sw[b * PP + p] = v[cnt++] * inv;

    for (int j = tid; j < TT; j += 256) out[b * FF + CC + j] = text[b * TT + j];
}

// ---------------------------------------------------------------------------
// K4: pooled[b,c] = sum_p vision[b,c,p] * weights[b,p] (unchanged).
// ---------------------------------------------------------------------------
__global__ __launch_bounds__(256) void k_pool(const float* __restrict__ vision,
                                              const float* __restrict__ wts,
                                              float* __restrict__ out) {
    const int cg = blockIdx.x;
    const int b  = blockIdx.y;
    const int tid = threadIdx.x, lane = tid & 63, wid = tid >> 6;
    __shared__ float wl[PP];
    {
        const int i = tid * 4;
        if (i < PP) *(float4*)&wl[i] = *(const float4*)&wts[b * PP + i];
    }
    __syncthreads();
    #pragma unroll
    for (int ci = 0; ci < 16; ++ci) {
        const int c = cg * 64 + wid * 16 + ci;
        const float* vr = vision + (size_t)b * (CC * PP) + (size_t)c * PP;
        float acc = 0.f;
        #pragma unroll
        for (int k = 0; k < 4; ++k) {
            const int p4 = (lane + 64 * k) * 4;
            if (p4 < PP) {
                const float4 vv = *(const float4*)(vr + p4);
                const float4 ww = *(const float4*)&wl[p4];
                acc = fmaf(vv.x, ww.x, acc);
                acc = fmaf(vv.y, ww.y, acc);
                acc = fmaf(vv.z, ww.z, acc);
                acc = fmaf(vv.w, ww.w, acc);
            }
        }
        #pragma unroll
        for (int off = 32; off > 0; off >>= 1) acc += __shfl_xor(acc, off, 64);
        if (lane == 0) out[b * FF + c] = acc;
    }
}

// ---------------------------------------------------------------------------
extern "C" void kernel_launch(void* const* d_in, const int* in_sizes, int n_in,
                              void* d_out, int out_size, void* d_ws, size_t ws_size,
                              hipStream_t stream) {
    const float* text   = (const float*)d_in[0];
    const float* vision = (const float*)d_in[1];
    const float* W1     = (const float*)d_in[2];
    const float* b1     = (const float*)d_in[3];
    const float* W2     = (const float*)d_in[4];
    float* out = (float*)d_out;

    // ws layout: tbp 512KB | sw 200KB | w1t_hi 256KB | w1t_lo 256KB  (~1.2 MB)
    float* tbp = (float*)d_ws;                       // 64*4*512 f32
    float* sw  = tbp + BB * 4 * HID;                 // 64*784 f32
    unsigned short* w1t_hi = (unsigned short*)(sw + BB * PP);   // 131072 bf16
    unsigned short* w1t_lo = w1t_hi + 131072;

    k_w1t        <<<64, 256, 0, stream>>>(W1, w1t_hi, w1t_lo);
    k_text_gemm  <<<dim3(BB, 4), 512, 0, stream>>>(text, W1, tbp);
    hipMemsetAsync(sw, 0, BB * PP * sizeof(float), stream);
    k_vision_mfma<<<dim3(7, 2, BB), 256, 0, stream>>>(vision, w1t_hi, w1t_lo,
                                                      b1, W2, tbp, sw);
    k_softmax_copy<<<BB, 256, 0, stream>>>(sw, text, out);
    k_pool       <<<dim3(4, BB), 256, 0, stream>>>(vision, sw, out);
}

// Round 6
// 175.003 us; speedup vs baseline: 1.6346x; 1.0572x over previous
//
#include <hip/hip_runtime.h>

#define BB  64
#define TT  1024
#define CC  256
#define PP  784     // 28*28
#define HID 512
#define FF  1280    // CC + TT

typedef float v4f __attribute__((ext_vector_type(4)));
typedef short v8s __attribute__((ext_vector_type(8)));

// round-to-nearest-even bf16; returns the f32 bit pattern of the bf16 value
__device__ inline unsigned int bf16_rne_bits(float x) {
    unsigned int u = __float_as_uint(x);
    unsigned int r = u + 0x7FFFu + ((u >> 16) & 1u);
    return r & 0xFFFF0000u;
}

// ---------------------------------------------------------------------------
// K0: precompute W1 vision-half as bf16 hi/lo in MFMA B-fragment image order:
// chunk (hh, ks) at elem offset (hh*8+ks)*8192; within: h'*32 + g*8 + e,
// where h'=h&255, c = ks*32 + g*8 + e.  512 KB total, done once.
// ---------------------------------------------------------------------------
__global__ __launch_bounds__(256) void k_w1t(const float* __restrict__ W1,
                                             unsigned short* __restrict__ w1t_hi,
                                             unsigned short* __restrict__ w1t_lo) {
    const int id = blockIdx.x * 256 + threadIdx.x;   // 16384 threads
    const int h  = id & 511;
    const int cg = id >> 9;                          // 0..31
    const int cstep = cg >> 2, g = cg & 3;
    const float* W1v = W1 + (size_t)TT * HID;
    unsigned int hw[4], lw[4];
    #pragma unroll
    for (int k = 0; k < 4; ++k) {
        const int c0 = cstep * 32 + g * 8 + 2 * k;
        float x0 = W1v[(size_t)c0 * HID + h];
        float x1 = W1v[(size_t)(c0 + 1) * HID + h];
        unsigned int h0 = bf16_rne_bits(x0), h1 = bf16_rne_bits(x1);
        unsigned int l0 = bf16_rne_bits(x0 - __uint_as_float(h0));
        unsigned int l1 = bf16_rne_bits(x1 - __uint_as_float(h1));
        hw[k] = (h0 >> 16) | (h1 & 0xFFFF0000u);
        lw[k] = (l0 >> 16) | (l1 & 0xFFFF0000u);
    }
    const size_t eoff = ((size_t)((h >> 8) * 8 + cstep) * 256 + (h & 255)) * 32 + g * 8;
    *(int4*)(&w1t_hi[eoff]) = make_int4(hw[0], hw[1], hw[2], hw[3]);
    *(int4*)(&w1t_lo[eoff]) = make_int4(lw[0], lw[1], lw[2], lw[3]);
}

// ---------------------------------------------------------------------------
// K1: text GEMM partials, k-split by 8 (512 blocks, 128-long FMA chains).
// tbp[b][ks][h] = sum_{k in 128-chunk} text[b,k] * W1[k,h]
// ---------------------------------------------------------------------------
__global__ __launch_bounds__(512) void k_text_gemm(const float* __restrict__ text,
                                                   const float* __restrict__ W1,
                                                   float* __restrict__ tbp) {
    const int b  = blockIdx.x;
    const int ks = blockIdx.y;    // 0..7
    const int t  = threadIdx.x;
    __shared__ float st[128];
    if (t < 128) st[t] = text[b * TT + ks * 128 + t];
    __syncthreads();
    float acc = 0.f;
    const float* wp = W1 + (size_t)(ks * 128) * HID + t;
    #pragma unroll 4
    for (int k = 0; k < 128; ++k)
        acc = fmaf(st[k], wp[(size_t)k * HID], acc);
    tbp[(b * 8 + ks) * HID + t] = acc;
}

// ---------------------------------------------------------------------------
// K2 (hot): vision GEMM via bf16 hi/lo split MFMA (3 terms).
// T3 2-phase structure: A (pixels) double-buffered in LDS with early-issued
// scattered loads (T14 split: load before MFMAs, convert+write after);
// B (W1T) read fragment-direct from global into registers (L2-resident,
// coalesced 16B/lane). One barrier per K-step. LDS 28.7 KB, ~190 VGPR.
// ---------------------------------------------------------------------------
__global__ __launch_bounds__(256, 2) void k_vision_mfma(
        const float* __restrict__ vision,
        const unsigned short* __restrict__ w1t_hi,
        const unsigned short* __restrict__ w1t_lo,
        const float* __restrict__ b1,
        const float* __restrict__ W2,
        const float* __restrict__ tbp,
        float* __restrict__ scores) {
    const int ptile = blockIdx.x;   // 0..6
    const int hh    = blockIdx.y;   // 0..1
    const int b     = blockIdx.z;
    const int tid   = threadIdx.x;
    const int lane  = tid & 63;
    const int w     = tid >> 6;     // 4 waves
    const int l15   = lane & 15, lg = lane >> 4;

    // A double-buffer: [buf][hi 7168B | lo 7168B]
    __shared__ int4 lds4[2][896];

    v4f acc[7][4];
    #pragma unroll
    for (int m = 0; m < 7; ++m)
        #pragma unroll
        for (int n = 0; n < 4; ++n) acc[m][n] = (v4f){0.f, 0.f, 0.f, 0.f};

    const size_t vbase = (size_t)b * (CC * PP) + ptile * 112;
    const int spx = tid >> 1, sch = tid & 1;   // staging map (tid < 224)

    float xv[16];
    #define A_LOAD(KS) do { if (tid < 224) { \
        _Pragma("unroll") for (int j = 0; j < 16; ++j) { \
            const int c_ = (KS) * 32 + sch * 16 + j; \
            xv[j] = vision[vbase + (size_t)c_ * PP + spx]; } } } while (0)

    #define A_WRITE(BUF) do { if (tid < 224) { \
        unsigned int hw[8], lw[8]; \
        _Pragma("unroll") for (int q = 0; q < 8; ++q) { \
            unsigned int h0 = bf16_rne_bits(xv[2 * q]); \
            unsigned int h1 = bf16_rne_bits(xv[2 * q + 1]); \
            unsigned int l0 = bf16_rne_bits(xv[2 * q] - __uint_as_float(h0)); \
            unsigned int l1 = bf16_rne_bits(xv[2 * q + 1] - __uint_as_float(h1)); \
            hw[q] = (h0 >> 16) | (h1 & 0xFFFF0000u); \
            lw[q] = (l0 >> 16) | (l1 & 0xFFFF0000u); } \
        int4* ah = (int4*)(&lds4[BUF][0]) + (spx * 4 + sch * 2); \
        int4* al = (int4*)((char*)&lds4[BUF][0] + 7168) + (spx * 4 + sch * 2); \
        ah[0] = make_int4(hw[0], hw[1], hw[2], hw[3]); \
        ah[1] = make_int4(hw[4], hw[5], hw[6], hw[7]); \
        al[0] = make_int4(lw[0], lw[1], lw[2], lw[3]); \
        al[1] = make_int4(lw[4], lw[5], lw[6], lw[7]); } } while (0)

    A_LOAD(0);
    A_WRITE(0);
    __syncthreads();

    // lane's B-fragment elem offset within a (hh,ks) chunk; n adds n*512
    const int bfr = ((w * 64 + l15) * 4 + lg) * 8;

    for (int ks = 0; ks < 8; ++ks) {
        const int cur = ks & 1;
        if (ks < 7) A_LOAD(ks + 1);              // scattered loads in flight
        // B fragments for this K-step -> registers (8 x 16B, L2-resident)
        const unsigned short* bkh = w1t_hi + (size_t)(hh * 8 + ks) * 8192 + bfr;
        const unsigned short* bkl = w1t_lo + (size_t)(hh * 8 + ks) * 8192 + bfr;
        v8s bh[4], bl[4];
        #pragma unroll
        for (int n = 0; n < 4; ++n) {
            bh[n] = *(const v8s*)(bkh + n * 512);
            bl[n] = *(const v8s*)(bkl + n * 512);
        }
        const char* abuf = (const char*)&lds4[cur][0];
        #pragma unroll
        for (int m = 0; m < 7; ++m) {
            const int fo = ((m * 16 + l15) * 4 + lg) * 16;
            const v8s ah = *(const v8s*)(abuf + fo);
            const v8s al = *(const v8s*)(abuf + 7168 + fo);
            #pragma unroll
            for (int n = 0; n < 4; ++n) {
                acc[m][n] = __builtin_amdgcn_mfma_f32_16x16x32_bf16(ah, bh[n], acc[m][n], 0, 0, 0);
                acc[m][n] = __builtin_amdgcn_mfma_f32_16x16x32_bf16(ah, bl[n], acc[m][n], 0, 0, 0);
                acc[m][n] = __builtin_amdgcn_mfma_f32_16x16x32_bf16(al, bh[n], acc[m][n], 0, 0, 0);
            }
        }
        if (ks < 7) A_WRITE(cur ^ 1);            // convert + stage after MFMAs
        __syncthreads();
    }

    // ---- epilogue: +text/bias, ReLU, *W2, reduce over h, atomic partial ----
    float tbn[4], w2n[4];
    #pragma unroll
    for (int n = 0; n < 4; ++n) {
        const int hglob = hh * 256 + w * 64 + n * 16 + l15;
        const float* tp = tbp + (size_t)b * 8 * HID + hglob;
        float tv = b1[hglob];
        #pragma unroll
        for (int q = 0; q < 8; ++q) tv += tp[q * HID];
        tbn[n] = tv;
        w2n[n] = W2[hglob];
    }
    const int px0 = ptile * 112 + lg * 4;
    #pragma unroll
    for (int m = 0; m < 7; ++m) {
        #pragma unroll
        for (int r = 0; r < 4; ++r) {
            float s = 0.f;
            #pragma unroll
            for (int n = 0; n < 4; ++n)
                s += fmaxf(acc[m][n][r] + tbn[n], 0.f) * w2n[n];
            s += __shfl_xor(s, 1, 64);
            s += __shfl_xor(s, 2, 64);
            s += __shfl_xor(s, 4, 64);
            s += __shfl_xor(s, 8, 64);
            if (l15 == 0)
                atomicAdd(&scores[b * PP + px0 + m * 16 + r], s);
        }
    }
    #undef A_LOAD
    #undef A_WRITE
}

// ---------------------------------------------------------------------------
// K3: softmax over P per batch row (in-place) + text passthrough.
// (b2 omitted everywhere: softmax is shift-invariant.)
// ---------------------------------------------------------------------------
__global__ __launch_bounds__(256) void k_softmax_copy(float* __restrict__ sw,
                                                      const float* __restrict__ text,
                                                      float* __restrict__ out) {
    const int b   = blockIdx.x;
    const int tid = threadIdx.x;
    const int lane = tid & 63, wid = tid >> 6;
    __shared__ float red[4];

    float v[4]; int cnt = 0;
    float m = -3.4e38f;
    for (int p = tid; p < PP; p += 256) { v[cnt] = sw[b * PP + p]; m = fmaxf(m, v[cnt]); ++cnt; }
    #pragma unroll
    for (int off = 32; off > 0; off >>= 1) m = fmaxf(m, __shfl_xor(m, off, 64));
    if (lane == 0) red[wid] = m;
    __syncthreads();
    m = fmaxf(fmaxf(red[0], red[1]), fmaxf(red[2], red[3]));
    __syncthreads();

    float ssum = 0.f;
    for (int i = 0; i < cnt; ++i) { v[i] = expf(v[i] - m); ssum += v[i]; }
    #pragma unroll
    for (int off = 32; off > 0; off >>= 1) ssum += __shfl_xor(ssum, off, 64);
    if (lane == 0) red[wid] = ssum;
    __syncthreads();
    const float inv = 1.f / (red[0] + red[1] + red[2] + red[3]);

    cnt = 0;
    for (int p = tid; p < PP; p += 256) sw[b * PP + p] = v[cnt++] * inv;

    for (int j = tid; j < TT; j += 256) out[b * FF + CC + j] = text[b * TT + j];
}

// ---------------------------------------------------------------------------
// K4: pooled[b,c] = sum_p vision[b,c,p] * weights[b,p]  (512 blocks).
// ---------------------------------------------------------------------------
__global__ __launch_bounds__(256) void k_pool(const float* __restrict__ vision,
                                              const float* __restrict__ wts,
                                              float* __restrict__ out) {
    const int cg = blockIdx.x;   // 8 channel groups of 32
    const int b  = blockIdx.y;
    const int tid = threadIdx.x, lane = tid & 63, wid = tid >> 6;  // 4 waves
    __shared__ float wl[PP];
    {
        const int i = tid * 4;
        if (i < PP) *(float4*)&wl[i] = *(const float4*)&wts[b * PP + i];
    }
    __syncthreads();
    #pragma unroll
    for (int ci = 0; ci < 8; ++ci) {
        const int c = cg * 32 + wid * 8 + ci;
        const float* vr = vision + (size_t)b * (CC * PP) + (size_t)c * PP;
        float acc = 0.f;
        #pragma unroll
        for (int k = 0; k < 4; ++k) {
            const int p4 = (lane + 64 * k) * 4;
            if (p4 < PP) {
                const float4 vv = *(const float4*)(vr + p4);
                const float4 ww = *(const float4*)&wl[p4];
                acc = fmaf(vv.x, ww.x, acc);
                acc = fmaf(vv.y, ww.y, acc);
                acc = fmaf(vv.z, ww.z, acc);
                acc = fmaf(vv.w, ww.w, acc);
            }
        }
        #pragma unroll
        for (int off = 32; off > 0; off >>= 1) acc += __shfl_xor(acc, off, 64);
        if (lane == 0) out[b * FF + c] = acc;
    }
}

// ---------------------------------------------------------------------------
extern "C" void kernel_launch(void* const* d_in, const int* in_sizes, int n_in,
                              void* d_out, int out_size, void* d_ws, size_t ws_size,
                              hipStream_t stream) {
    const float* text   = (const float*)d_in[0];
    const float* vision = (const float*)d_in[1];
    const float* W1     = (const float*)d_in[2];
    const float* b1     = (const float*)d_in[3];
    const float* W2     = (const float*)d_in[4];
    float* out = (float*)d_out;

    // ws layout: tbp 1MB | sw 200KB | w1t_hi 256KB | w1t_lo 256KB  (~1.7 MB)
    float* tbp = (float*)d_ws;                       // 64*8*512 f32
    float* sw  = tbp + BB * 8 * HID;                 // 64*784 f32
    unsigned short* w1t_hi = (unsigned short*)(sw + BB * PP);   // 131072 bf16
    unsigned short* w1t_lo = w1t_hi + 131072;

    k_w1t        <<<64, 256, 0, stream>>>(W1, w1t_hi, w1t_lo);
    k_text_gemm  <<<dim3(BB, 8), 512, 0, stream>>>(text, W1, tbp);
    hipMemsetAsync(sw, 0, BB * PP * sizeof(float), stream);
    k_vision_mfma<<<dim3(7, 2, BB), 256, 0, stream>>>(vision, w1t_hi, w1t_lo,
                                                      b1, W2, tbp, sw);
    k_softmax_copy<<<BB, 256, 0, stream>>>(sw, text, out);
    k_pool       <<<dim3(8, BB), 256, 0, stream>>>(vision, sw, out);
}